// Round 1
// baseline (201.035 us; speedup 1.0000x reference)
//
#include <hip/hip_runtime.h>
#include <cmath>
#include <cstdint>

#define NB 32
#define NP 24564
#define NC 81
#define NEG_POS 3

static constexpr size_t MINED_ELEMS = (size_t)NB * NP;          // 786,048
static constexpr size_t MINED_BYTES = MINED_ELEMS * sizeof(float); // 3,144,192 (8B aligned)

// ws layout:
//   [0, MINED_BYTES)                    float mined[NB*NP]
//   [MINED_BYTES, +24)                  double acc[3]  {loc_loss, ce_pos_sum, neg_sum}
//   [MINED_BYTES+24, +24+4*NB)          int   num_pos[NB]

__device__ __forceinline__ float wave_reduce_sum(float v) {
#pragma unroll
  for (int off = 32; off > 0; off >>= 1) v += __shfl_down(v, off, 64);
  return v;
}

__global__ void mb_init(double* __restrict__ acc, int* __restrict__ num_pos) {
  int t = threadIdx.x;
  if (t < 3) acc[t] = 0.0;
  if (t < NB) num_pos[t] = 0;
}

__global__ __launch_bounds__(256) void mb_main(
    const float* __restrict__ loc_data, const float* __restrict__ conf_data,
    const float* __restrict__ loc_targets, const int* __restrict__ conf_targets,
    float* __restrict__ mined, double* __restrict__ acc, int* __restrict__ num_pos) {
  const int b = blockIdx.y;
  const int p = blockIdx.x * 256 + (int)threadIdx.x;

  float loc_v = 0.f;
  float ce_pos = 0.f;
  int is_pos = 0;

  if (p < NP) {
    const size_t idx = (size_t)b * NP + p;
    const int tgt = conf_targets[idx];
    const float* __restrict__ row = conf_data + idx * (size_t)NC;

    // online logsumexp over 81 classes
    float m = -INFINITY, s = 0.f;
#pragma unroll 9
    for (int c = 0; c < NC; ++c) {
      float x = row[c];
      float m2 = fmaxf(m, x);
      s = s * __expf(m - m2) + __expf(x - m2);
      m = m2;
    }
    const float ce = m + __logf(s) - row[tgt];

    is_pos = (tgt > 0) ? 1 : 0;
    mined[idx] = is_pos ? 0.f : ce;   // ce >= log(s) > 0 always, so bits order as floats

    if (is_pos) {
      ce_pos = ce;
      const float4 a = *reinterpret_cast<const float4*>(loc_data + idx * 4);
      const float4 t = *reinterpret_cast<const float4*>(loc_targets + idx * 4);
      float d, ax;
      d = a.x - t.x; ax = fabsf(d); loc_v += (ax < 1.f) ? 0.5f * d * d : ax - 0.5f;
      d = a.y - t.y; ax = fabsf(d); loc_v += (ax < 1.f) ? 0.5f * d * d : ax - 0.5f;
      d = a.z - t.z; ax = fabsf(d); loc_v += (ax < 1.f) ? 0.5f * d * d : ax - 0.5f;
      d = a.w - t.w; ax = fabsf(d); loc_v += (ax < 1.f) ? 0.5f * d * d : ax - 0.5f;
    }
  }

  // block reduction (4 waves)
  __shared__ float red[3][4];
  const int lane = threadIdx.x & 63;
  const int wid = threadIdx.x >> 6;
  float r0 = wave_reduce_sum(loc_v);
  float r1 = wave_reduce_sum(ce_pos);
  float r2 = wave_reduce_sum((float)is_pos);
  if (lane == 0) { red[0][wid] = r0; red[1][wid] = r1; red[2][wid] = r2; }
  __syncthreads();
  if (threadIdx.x == 0) {
    float t0 = 0.f, t1 = 0.f, t2 = 0.f;
#pragma unroll
    for (int i = 0; i < 4; ++i) { t0 += red[0][i]; t1 += red[1][i]; t2 += red[2][i]; }
    if (t0 != 0.f) atomicAdd(&acc[0], (double)t0);
    if (t1 != 0.f) atomicAdd(&acc[1], (double)t1);
    const int np = (int)t2;
    if (np) atomicAdd(&num_pos[b], np);
  }
}

// One block per batch row: radix-select the (k+1)-th largest of mined[b,:]
// (k = min(3*num_pos, NP-1)), then sum elements strictly greater.
__global__ __launch_bounds__(1024) void mb_select(
    const float* __restrict__ mined, const int* __restrict__ num_pos,
    double* __restrict__ acc) {
  const int b = blockIdx.x;
  const float* __restrict__ row = mined + (size_t)b * NP;
  const int tid = threadIdx.x;

  __shared__ int hist[256];
  __shared__ unsigned s_prefix;
  __shared__ int s_k;

  if (tid == 0) {
    int k = NEG_POS * num_pos[b];
    if (k > NP - 1) k = NP - 1;
    s_k = k;          // 0-indexed rank in descending order
    s_prefix = 0u;
  }
  __syncthreads();

  for (int shift = 24; shift >= 0; shift -= 8) {
    for (int i = tid; i < 256; i += 1024) hist[i] = 0;
    __syncthreads();
    const unsigned mask = (shift == 24) ? 0u : (0xFFFFFFFFu << (shift + 8));
    const unsigned pfx = s_prefix;
    for (int p = tid; p < NP; p += 1024) {
      const unsigned u = __float_as_uint(row[p]);
      if ((u & mask) == pfx) atomicAdd(&hist[(u >> shift) & 255], 1);
    }
    __syncthreads();
    if (tid == 0) {
      int k = s_k;
      int cum = 0;
      int bin = 255;
      for (; bin >= 0; --bin) {
        if (cum + hist[bin] > k) break;   // rank-k element lives in this bin
        cum += hist[bin];
      }
      s_k = k - cum;
      s_prefix = pfx | ((unsigned)bin << shift);
    }
    __syncthreads();
  }

  const unsigned vbits = s_prefix;  // exact bit pattern of pivot value
  float sum = 0.f;
  for (int p = tid; p < NP; p += 1024) {
    const float x = row[p];
    if (__float_as_uint(x) > vbits) sum += x;  // strict >, matches "mined > pivot"
  }

  __shared__ float wsum[16];
  float w = wave_reduce_sum(sum);
  if ((tid & 63) == 0) wsum[tid >> 6] = w;
  __syncthreads();
  if (tid == 0) {
    float t = 0.f;
#pragma unroll
    for (int i = 0; i < 16; ++i) t += wsum[i];
    atomicAdd(&acc[2], (double)t);
  }
}

__global__ void mb_finalize(const double* __restrict__ acc,
                            const int* __restrict__ num_pos,
                            float* __restrict__ out) {
  if (threadIdx.x == 0) {
    int tot = 0;
#pragma unroll
    for (int i = 0; i < NB; ++i) tot += num_pos[i];
    const double n = (double)(tot > 0 ? tot : 1);
    out[0] = (float)((acc[0] + acc[1] + acc[2]) / n);
  }
}

extern "C" void kernel_launch(void* const* d_in, const int* in_sizes, int n_in,
                              void* d_out, int out_size, void* d_ws, size_t ws_size,
                              hipStream_t stream) {
  const float* loc_data     = (const float*)d_in[0];
  const float* conf_data    = (const float*)d_in[1];
  const float* loc_targets  = (const float*)d_in[2];
  const int*   conf_targets = (const int*)d_in[3];
  float* out = (float*)d_out;

  float*  mined   = (float*)d_ws;
  double* acc     = (double*)((char*)d_ws + MINED_BYTES);
  int*    num_pos = (int*)((char*)d_ws + MINED_BYTES + 3 * sizeof(double));

  mb_init<<<1, 64, 0, stream>>>(acc, num_pos);

  dim3 grid((NP + 255) / 256, NB);
  mb_main<<<grid, 256, 0, stream>>>(loc_data, conf_data, loc_targets, conf_targets,
                                    mined, acc, num_pos);

  mb_select<<<NB, 1024, 0, stream>>>(mined, num_pos, acc);

  mb_finalize<<<1, 64, 0, stream>>>(acc, num_pos, out);
}